// Round 9
// baseline (564.048 us; speedup 1.0000x reference)
//
#include <hip/hip_runtime.h>
#include <stdint.h>

#define T_TOK 1024
#define H_DIM 2048
#define I_DIM 1408
#define IPAD 1536     // I_DIM padded to BN=256 multiple (G/U col stride)
#define E_NUM 16
#define K_TOP 6
#define PADCAP 8192   // max padded gathered rows: 6144 + 16*127 <= 8176
#define NE_ALL 18     // 16 routed + 2 shared pseudo-experts

typedef __attribute__((ext_vector_type(8))) short short8;
typedef __attribute__((ext_vector_type(8))) unsigned short ushort8;
typedef __attribute__((ext_vector_type(4))) float f32x4;

__device__ __forceinline__ unsigned short f2b(float f) {
    unsigned u = __float_as_uint(f);
    u += 0x7fffu + ((u >> 16) & 1u);   // round-to-nearest-even
    return (unsigned short)(u >> 16);
}
__device__ __forceinline__ float b2f(unsigned short s) {
    return __uint_as_float((unsigned)s << 16);
}

// packed f32x2 -> bf16x2 (RNE), single VALU op
__device__ __forceinline__ unsigned cvt_pk2(float a, float b) {
    unsigned r;
    asm("v_cvt_pk_bf16_f32 %0, %1, %2" : "=v"(r) : "v"(a), "v"(b));
    return r;
}

// async global->LDS, 16B per lane; LDS dest is wave-uniform base + lane*16
typedef __attribute__((address_space(1))) const unsigned int as1_uint;
typedef __attribute__((address_space(3))) unsigned int as3_uint;
__device__ __forceinline__ void gload16(const void* g, void* l) {
    __builtin_amdgcn_global_load_lds((as1_uint*)g, (as3_uint*)l, 16, 0, 0);
}

#define SCHED0() __builtin_amdgcn_sched_barrier(0)

// chunked bijective XCD swizzle
__device__ __forceinline__ int xcd_swizzle(int bid, int nwg) {
    const int q = nwg >> 3, r = nwg & 7;
    const int xcd = bid & 7, k = bid >> 3;
    const int base = (xcd < r) ? xcd * (q + 1) : r * (q + 1) + (xcd - r) * q;
    return base + k;
}

// ---------------- router ---------------------------------------------------
__global__ __launch_bounds__(256) void router_kernel(
    const float* __restrict__ x, const float* __restrict__ gw,
    float* __restrict__ topw, int* __restrict__ eidx, int* __restrict__ slotarr,
    int* __restrict__ counts)
{
    const int t = blockIdx.x, tid = threadIdx.x;
    const int lane = tid & 63, wave = tid >> 6;
    float part[E_NUM];
#pragma unroll
    for (int e = 0; e < E_NUM; ++e) part[e] = 0.f;
    const float* xr = x + (size_t)t * H_DIM;
    for (int i = tid; i < H_DIM; i += 256) {
        float xv = xr[i];
#pragma unroll
        for (int e = 0; e < E_NUM; ++e) part[e] += xv * gw[e * H_DIM + i];
    }
    __shared__ float red[4][E_NUM];
#pragma unroll
    for (int e = 0; e < E_NUM; ++e) {
        float v = part[e];
        for (int off = 32; off; off >>= 1) v += __shfl_down(v, off);
        if (lane == 0) red[wave][e] = v;
    }
    __syncthreads();
    if (tid == 0) {
        float logits[E_NUM];
#pragma unroll
        for (int e = 0; e < E_NUM; ++e)
            logits[e] = red[0][e] + red[1][e] + red[2][e] + red[3][e];
        int sel[K_TOP]; float selv[K_TOP];
        unsigned used = 0;
        for (int k = 0; k < K_TOP; ++k) {
            int best = 0; float bv = -1e30f;
            for (int e = 0; e < E_NUM; ++e)
                if (!((used >> e) & 1u) && logits[e] > bv) { bv = logits[e]; best = e; }
            used |= 1u << best; sel[k] = best; selv[k] = bv;
        }
        float mx = selv[0], s = 0.f, w[K_TOP];
        for (int k = 0; k < K_TOP; ++k) { w[k] = expf(selv[k] - mx); s += w[k]; }
        float inv = 1.f / s;
        for (int k = 0; k < K_TOP; ++k) {
            int slot = atomicAdd(&counts[sel[k]], 1);
            topw[t * K_TOP + k] = w[k] * inv;
            eidx[t * K_TOP + k] = sel[k];
            slotarr[t * K_TOP + k] = slot;
        }
    }
}

__global__ void zero_counts_kernel(int* counts) {
    if (threadIdx.x < E_NUM) counts[threadIdx.x] = 0;
}

__global__ void prefix_kernel(const int* __restrict__ counts, int* __restrict__ offs) {
    if (threadIdx.x == 0) {
        int o = 0;
        for (int e = 0; e < E_NUM; ++e) { offs[e] = o; o += (counts[e] + 127) & ~127; }
        offs[E_NUM] = o;   // start of shared-token rows
    }
}

// gather routed rows + shared token rows into Xall (bf16)
__global__ __launch_bounds__(256) void gather_cvt_kernel(
    const float* __restrict__ x, const int* __restrict__ eidx,
    const int* __restrict__ slotarr, const int* __restrict__ offs,
    ushort* __restrict__ Xall)
{
    const int b = blockIdx.x;
    int t; size_t row;
    if (b < T_TOK * K_TOP) {
        t = b / K_TOP;
        row = (size_t)offs[eidx[b]] + (size_t)slotarr[b];
    } else {
        t = b - T_TOK * K_TOP;
        row = (size_t)offs[E_NUM] + (size_t)t;
    }
    const float* src = x + (size_t)t * H_DIM;
    ushort* dst = Xall + row * H_DIM;
    const int i = threadIdx.x * 8;
    float4 f0 = *(const float4*)(src + i);
    float4 f1 = *(const float4*)(src + i + 4);
    ushort8 v;
    v[0] = f2b(f0.x); v[1] = f2b(f0.y); v[2] = f2b(f0.z); v[3] = f2b(f0.w);
    v[4] = f2b(f1.x); v[5] = f2b(f1.y); v[6] = f2b(f1.z); v[7] = f2b(f1.w);
    *(ushort8*)(dst + i) = v;
}

// ---------------- unified MoE GEMM (T3-minimum 2-phase, BM128 x BN256) -----
// C[M,N] = A[M,K](bf16) * B[N,K](fp32)^T, 18 experts. 512 threads = 8 waves
// (2M x 4N), per-wave 64x64 = acc[4][4] -> 0.5 ds_read per MFMA.
// LDS 96KB (1 block/CU): A dbuf 2x16KB via global_load_lds; B dbuf 2x32KB
// reg-staged fp32 -> cvt_pk bf16 (zero-conflict stripe layout, meas. r2/r6).
// ONE __syncthreads per K-step; staging issued BEFORE compute (T3 recipe):
// writeB's dep-wait is counted vmcnt(2) (A stays in flight a full phase).
// BN=256 pads N: B rows clamped to NB-1, C uses padded ldc.
template<int DOWN>
__global__ __launch_bounds__(512, 2) void moe_gemm_kernel(
    const ushort* __restrict__ Abase,
    const float* __restrict__ Wr1, const float* __restrict__ Wr2,
    const float* __restrict__ Ws1, const float* __restrict__ Ws2,
    ushort* __restrict__ C1, ushort* __restrict__ C2,
    const int* __restrict__ counts, const int* __restrict__ offs,
    int nNT, int lda, int K, int ldc)
{
    __shared__ short Alds[2][128 * 64];     // 2 x 16 KB
    __shared__ short Blds[2][256 * 64];     // 2 x 32 KB

    const int work = xcd_swizzle(blockIdx.x, gridDim.x);
    const int slab = NE_ALL * 8;
    int nt = work / slab;
    const int rem = work - nt * slab;
    const int e = rem >> 3;
    const int mt = rem & 7;

    const int S = offs[E_NUM];
    const int M = (e < E_NUM) ? counts[e] : 1024;
    const int row0 = mt << 7;
    if (row0 >= M) return;
    const int crowbase = (e < E_NUM) ? offs[e] : S + ((e - E_NUM) << 10);
    const int arowbase = DOWN ? crowbase : ((e < E_NUM) ? offs[e] : S);

    const float* B; ushort* C; int ldb, koff = 0, NB;
    if (DOWN) {
        NB = H_DIM; C = C1;
        if (e < E_NUM) { ldb = I_DIM; B = Wr1 + (size_t)e * H_DIM * I_DIM; }
        else           { ldb = 2 * I_DIM; B = Ws1; koff = (e - E_NUM) * I_DIM; }
    } else {
        NB = I_DIM; ldb = H_DIM;
        const float* Bg = (e < E_NUM) ? Wr1 + (size_t)e * I_DIM * H_DIM
                                      : Ws1 + (size_t)(e - E_NUM) * I_DIM * H_DIM;
        const float* Bu = (e < E_NUM) ? Wr2 + (size_t)e * I_DIM * H_DIM
                                      : Ws2 + (size_t)(e - E_NUM) * I_DIM * H_DIM;
        if (nt < nNT) { B = Bg; C = C1; } else { B = Bu; C = C2; nt -= nNT; }
    }
    const int n0 = nt << 8;    // BN = 256

    const int tid = threadIdx.x;
    const int lane = tid & 63;
    const int wave = tid >> 6;                 // 0..7
    const int wm = wave >> 2, wn = wave & 3;   // 2M x 4N
    const int l15 = lane & 15, lhi = lane >> 4;

    const char* __restrict__ Ab = (const char*)(Abase + (size_t)(arowbase + row0) * lda);

    // A staging: 16 chunks of 1KB (8 rows x 128B); wave w stages chunks 2w,2w+1
    int aOff[2];
#pragma unroll
    for (int i = 0; i < 2; ++i) {
        const int chunk = wave * 2 + i;
        const int off = chunk * 1024 + lane * 16;
        const int r = off >> 7, s = (off >> 4) & 7;
        aOff[i] = r * lda * 2 + ((s ^ (r & 7)) << 4);   // bytes; +kt*128 later
    }

    // B staging: 2048 cells (row, 8-f32 slot = 32B); thread covers tid + j*512
    // (stripe pattern: each wave's 64 lanes = 8 rows x 8 slots -> conflict-free)
    const int brow = tid >> 3, bsl = tid & 7;
    const float* Bc[4]; int bldw[4];
#pragma unroll
    for (int j = 0; j < 4; ++j) {
        const int rl = brow + (j << 6);
        const int rg = min(n0 + rl, NB - 1);     // clamp: pad tiles re-read last row
        Bc[j] = B + (size_t)rg * ldb + koff + (bsl << 3);
        bldw[j] = (rl << 6) + ((bsl ^ (rl & 7)) << 3);
    }

    f32x4 acc[4][4];
#pragma unroll
    for (int m = 0; m < 4; ++m)
#pragma unroll
        for (int n = 0; n < 4; ++n) acc[m][n] = (f32x4){0.f, 0.f, 0.f, 0.f};

    float4 br[4][2];

    auto issueA = [&](int kt, int pb) {
#pragma unroll
        for (int i = 0; i < 2; ++i)
            gload16(Ab + (size_t)aOff[i] + (size_t)(kt << 7),
                    (char*)Alds[pb] + (wave * 2 + i) * 1024);
    };
    auto issueB = [&](int kt) {
#pragma unroll
        for (int j = 0; j < 4; ++j) {
            const float* src = Bc[j] + (kt << 6);
            br[j][0] = *(const float4*)src;
            br[j][1] = *(const float4*)(src + 4);
        }
    };
    auto writeB = [&](int pb) {
#pragma unroll
        for (int j = 0; j < 4; ++j) {
            union { short8 s; unsigned u[4]; } w;
            w.u[0] = cvt_pk2(br[j][0].x, br[j][0].y);
            w.u[1] = cvt_pk2(br[j][0].z, br[j][0].w);
            w.u[2] = cvt_pk2(br[j][1].x, br[j][1].y);
            w.u[3] = cvt_pk2(br[j][1].z, br[j][1].w);
            *(short8*)&Blds[pb][bldw[j]] = w.s;
        }
    };
    auto compute = [&](int p) {
#pragma unroll
        for (int kk = 0; kk < 2; ++kk) {
            const int kb = (kk << 2) + lhi;
            short8 af[4], bfr[4];
#pragma unroll
            for (int m = 0; m < 4; ++m) {
                const int rA = (wm << 6) + (m << 4) + l15;
                af[m] = *(const short8*)&Alds[p][(rA << 6) + ((kb ^ (rA & 7)) << 3)];
            }
#pragma unroll
            for (int n = 0; n < 4; ++n) {
                const int rB = (wn << 6) + (n << 4) + l15;
                bfr[n] = *(const short8*)&Blds[p][(rB << 6) + ((kb ^ (rB & 7)) << 3)];
            }
            __builtin_amdgcn_s_setprio(1);
#pragma unroll
            for (int m = 0; m < 4; ++m)
#pragma unroll
                for (int n = 0; n < 4; ++n)
                    acc[m][n] = __builtin_amdgcn_mfma_f32_16x16x32_bf16(
                        af[m], bfr[n], acc[m][n], 0, 0, 0);
            __builtin_amdgcn_s_setprio(0);
        }
    };

    const int nK = K >> 6;   // 32 (gate/up) or 22 (down)
    // prologue: stage tile 0
    issueA(0, 0); SCHED0();
    issueB(0); SCHED0();
    writeB(0);                // dep-wait counted: A(0) stays in flight
    __syncthreads();          // drains A(0) + B writes

    int p = 0;
    for (int kt = 0; kt < nK; ++kt) {
        const bool more = (kt + 1 < nK);
        if (more) {
            issueA(kt + 1, p ^ 1); SCHED0();   // oldest: full phase of cover
            issueB(kt + 1); SCHED0();
        }
        compute(p);                            // 64 MFMA + 16 ds_read per wave
        if (more) writeB(p ^ 1);               // dep-wait vmcnt(2): A in flight
        __syncthreads();                       // ONE barrier/K-step
        p ^= 1;
    }

    // epilogue: C/D layout col=lane&15, row=(lane>>4)*4+j
    const size_t cbase_col = (size_t)n0 + (wn << 6) + l15;
#pragma unroll
    for (int m = 0; m < 4; ++m) {
        const int rloc = (wm << 6) + (m << 4) + (lhi << 2);
#pragma unroll
        for (int j = 0; j < 4; ++j) {
            const int crow = row0 + rloc + j;
            if (crow >= M) continue;
            const size_t co = (size_t)(crowbase + crow) * ldc + cbase_col;
#pragma unroll
            for (int n = 0; n < 4; ++n) C[co + (n << 4)] = f2b(acc[m][n][j]);
        }
    }
}

// ---------------- SwiGLU elementwise: G = silu(G) * U (stride IPAD) --------
__global__ __launch_bounds__(256) void silu_kernel(
    ushort* __restrict__ G, const ushort* __restrict__ U,
    const int* __restrict__ eidx, const int* __restrict__ slotarr,
    const int* __restrict__ offs)
{
    const int b = blockIdx.x;
    size_t row;
    if (b < T_TOK * K_TOP) {
        row = (size_t)offs[eidx[b]] + (size_t)slotarr[b];
    } else {
        row = (size_t)offs[E_NUM] + (size_t)(b - T_TOK * K_TOP);
    }
    ushort* g = G + row * IPAD;
    const ushort* u = U + row * IPAD;
    const int i = threadIdx.x * 8;
    if (i < I_DIM) {
        ushort8 gv = *(const ushort8*)(g + i);
        ushort8 uv = *(const ushort8*)(u + i);
        ushort8 hv;
#pragma unroll
        for (int j = 0; j < 8; ++j) {
            float gf = b2f(gv[j]);
            float uf = b2f(uv[j]);
            float sf = gf / (1.f + expf(-gf));
            hv[j] = f2b(sf * uf);
        }
        *(ushort8*)(g + i) = hv;
    }
}

// ---------------- combine: out[t] = sum_k w_k*Y[row] + Y[sh0] + Y[sh1] -----
__global__ __launch_bounds__(256) void combine_kernel(
    float* __restrict__ out, const ushort* __restrict__ Y,
    const float* __restrict__ topw, const int* __restrict__ eidx,
    const int* __restrict__ slotarr, const int* __restrict__ offs)
{
    const int t = blockIdx.x;
    const int i = threadIdx.x * 8;
    const int S = offs[E_NUM];
    float acc[8];
    {
        ushort8 v0 = *(const ushort8*)(Y + ((size_t)S + t) * H_DIM + i);
        ushort8 v1 = *(const ushort8*)(Y + ((size_t)S + 1024 + t) * H_DIM + i);
#pragma unroll
        for (int j = 0; j < 8; ++j) acc[j] = b2f(v0[j]) + b2f(v1[j]);
    }
#pragma unroll
    for (int k = 0; k < K_TOP; ++k) {
        const float w = topw[t * K_TOP + k];
        const size_t row = (size_t)offs[eidx[t * K_TOP + k]] + (size_t)slotarr[t * K_TOP + k];
        ushort8 v = *(const ushort8*)(Y + row * H_DIM + i);
#pragma unroll
        for (int j = 0; j < 8; ++j) acc[j] += w * b2f(v[j]);
    }
    float* o = out + (size_t)t * H_DIM;
    float4 o0, o1;
    o0.x = acc[0]; o0.y = acc[1]; o0.z = acc[2]; o0.w = acc[3];
    o1.x = acc[4]; o1.y = acc[5]; o1.z = acc[6]; o1.w = acc[7];
    *(float4*)(o + i) = o0;
    *(float4*)(o + i + 4) = o1;
}

// ---------------------------------------------------------------------------
extern "C" void kernel_launch(void* const* d_in, const int* in_sizes, int n_in,
                              void* d_out, int out_size, void* d_ws, size_t ws_size,
                              hipStream_t stream) {
    const float* x       = (const float*)d_in[0];
    const float* gate_w  = (const float*)d_in[1];
    const float* w_gate  = (const float*)d_in[2];
    const float* w_up    = (const float*)d_in[3];
    const float* w_down  = (const float*)d_in[4];
    const float* sw_gate = (const float*)d_in[5];
    const float* sw_up   = (const float*)d_in[6];
    const float* sw_down = (const float*)d_in[7];
    float* out = (float*)d_out;

    char* p = (char*)d_ws;
    auto take = [&](size_t b) { char* r = p; p += (b + 255) & ~(size_t)255; return r; };
    int*    counts = (int*)take(32 * 4);
    int*    offs   = (int*)take(32 * 4);
    float*  topw   = (float*)take((size_t)T_TOK * K_TOP * 4);
    int*    eidx   = (int*)take((size_t)T_TOK * K_TOP * 4);
    int*    slot   = (int*)take((size_t)T_TOK * K_TOP * 4);
    ushort* Xall   = (ushort*)take((size_t)(PADCAP + 1024) * H_DIM * 2);
    ushort* G      = (ushort*)take((size_t)(PADCAP + 2048) * IPAD * 2);
    ushort* U      = (ushort*)take((size_t)(PADCAP + 2048) * IPAD * 2);
    ushort* Y      = (ushort*)take((size_t)(PADCAP + 2048) * H_DIM * 2);

    zero_counts_kernel<<<1, 64, 0, stream>>>(counts);
    router_kernel<<<T_TOK, 256, 0, stream>>>(x, gate_w, topw, eidx, slot, counts);
    prefix_kernel<<<1, 64, 0, stream>>>(counts, offs);
    gather_cvt_kernel<<<T_TOK * K_TOP + T_TOK, 256, 0, stream>>>(x, eidx, slot, offs, Xall);

    // gate/up: 12 n-tiles (6 gate + 6 up, BN=256 padded) x 18 experts x 8 m-tiles
    moe_gemm_kernel<0><<<12 * NE_ALL * 8, 512, 0, stream>>>(
        Xall, w_gate, w_up, sw_gate, sw_up, G, U, counts, offs,
        6, H_DIM /*lda*/, H_DIM /*K*/, IPAD /*ldc*/);
    silu_kernel<<<T_TOK * K_TOP + 2048, 256, 0, stream>>>(G, U, eidx, slot, offs);
    // down: 8 n-tiles (BN=256) x 18 experts x 8 m-tiles, K=1408, A stride IPAD
    moe_gemm_kernel<1><<<8 * NE_ALL * 8, 512, 0, stream>>>(
        G, w_down, nullptr, sw_down, nullptr, Y, nullptr, counts, offs,
        8, IPAD /*lda*/, I_DIM /*K*/, H_DIM /*ldc*/);

    combine_kernel<<<T_TOK, 256, 0, stream>>>(out, Y, topw, eidx, slot, offs);
}

// Round 10
// 467.623 us; speedup vs baseline: 1.2062x; 1.2062x over previous
//
#include <hip/hip_runtime.h>
#include <stdint.h>

#define T_TOK 1024
#define H_DIM 2048
#define I_DIM 1408
#define E_NUM 16
#define K_TOP 6
#define PADCAP 8192   // max padded gathered rows: 6144 + 16*127 <= 8176
#define NE_ALL 18     // 16 routed + 2 shared pseudo-experts

typedef __attribute__((ext_vector_type(8))) short short8;
typedef __attribute__((ext_vector_type(8))) unsigned short ushort8;
typedef __attribute__((ext_vector_type(4))) float f32x4;

__device__ __forceinline__ unsigned short f2b(float f) {
    unsigned u = __float_as_uint(f);
    u += 0x7fffu + ((u >> 16) & 1u);   // round-to-nearest-even
    return (unsigned short)(u >> 16);
}
__device__ __forceinline__ float b2f(unsigned short s) {
    return __uint_as_float((unsigned)s << 16);
}

// packed f32x2 -> bf16x2 (RNE), single VALU op
__device__ __forceinline__ unsigned cvt_pk2(float a, float b) {
    unsigned r;
    asm("v_cvt_pk_bf16_f32 %0, %1, %2" : "=v"(r) : "v"(a), "v"(b));
    return r;
}

// async global->LDS, 16B per lane; LDS dest is wave-uniform base + lane*16
typedef __attribute__((address_space(1))) const unsigned int as1_uint;
typedef __attribute__((address_space(3))) unsigned int as3_uint;
__device__ __forceinline__ void gload16(const void* g, void* l) {
    __builtin_amdgcn_global_load_lds((as1_uint*)g, (as3_uint*)l, 16, 0, 0);
}

#define SCHED0() __builtin_amdgcn_sched_barrier(0)
#define RBAR() __builtin_amdgcn_s_barrier()

// chunked bijective XCD swizzle
__device__ __forceinline__ int xcd_swizzle(int bid, int nwg) {
    const int q = nwg >> 3, r = nwg & 7;
    const int xcd = bid & 7, k = bid >> 3;
    const int base = (xcd < r) ? xcd * (q + 1) : r * (q + 1) + (xcd - r) * q;
    return base + k;
}

// ---------------- router ---------------------------------------------------
__global__ __launch_bounds__(256) void router_kernel(
    const float* __restrict__ x, const float* __restrict__ gw,
    float* __restrict__ topw, int* __restrict__ eidx, int* __restrict__ slotarr,
    int* __restrict__ counts)
{
    const int t = blockIdx.x, tid = threadIdx.x;
    const int lane = tid & 63, wave = tid >> 6;
    float part[E_NUM];
#pragma unroll
    for (int e = 0; e < E_NUM; ++e) part[e] = 0.f;
    const float* xr = x + (size_t)t * H_DIM;
    for (int i = tid; i < H_DIM; i += 256) {
        float xv = xr[i];
#pragma unroll
        for (int e = 0; e < E_NUM; ++e) part[e] += xv * gw[e * H_DIM + i];
    }
    __shared__ float red[4][E_NUM];
#pragma unroll
    for (int e = 0; e < E_NUM; ++e) {
        float v = part[e];
        for (int off = 32; off; off >>= 1) v += __shfl_down(v, off);
        if (lane == 0) red[wave][e] = v;
    }
    __syncthreads();
    if (tid == 0) {
        float logits[E_NUM];
#pragma unroll
        for (int e = 0; e < E_NUM; ++e)
            logits[e] = red[0][e] + red[1][e] + red[2][e] + red[3][e];
        int sel[K_TOP]; float selv[K_TOP];
        unsigned used = 0;
        for (int k = 0; k < K_TOP; ++k) {
            int best = 0; float bv = -1e30f;
            for (int e = 0; e < E_NUM; ++e)
                if (!((used >> e) & 1u) && logits[e] > bv) { bv = logits[e]; best = e; }
            used |= 1u << best; sel[k] = best; selv[k] = bv;
        }
        float mx = selv[0], s = 0.f, w[K_TOP];
        for (int k = 0; k < K_TOP; ++k) { w[k] = expf(selv[k] - mx); s += w[k]; }
        float inv = 1.f / s;
        for (int k = 0; k < K_TOP; ++k) {
            int slot = atomicAdd(&counts[sel[k]], 1);
            topw[t * K_TOP + k] = w[k] * inv;
            eidx[t * K_TOP + k] = sel[k];
            slotarr[t * K_TOP + k] = slot;
        }
    }
}

__global__ void zero_counts_kernel(int* counts) {
    if (threadIdx.x < E_NUM) counts[threadIdx.x] = 0;
}

__global__ void prefix_kernel(const int* __restrict__ counts, int* __restrict__ offs) {
    if (threadIdx.x == 0) {
        int o = 0;
        for (int e = 0; e < E_NUM; ++e) { offs[e] = o; o += (counts[e] + 127) & ~127; }
        offs[E_NUM] = o;   // start of shared-token rows
    }
}

// gather routed rows + shared token rows into Xall (bf16)
__global__ __launch_bounds__(256) void gather_cvt_kernel(
    const float* __restrict__ x, const int* __restrict__ eidx,
    const int* __restrict__ slotarr, const int* __restrict__ offs,
    ushort* __restrict__ Xall)
{
    const int b = blockIdx.x;
    int t; size_t row;
    if (b < T_TOK * K_TOP) {
        t = b / K_TOP;
        row = (size_t)offs[eidx[b]] + (size_t)slotarr[b];
    } else {
        t = b - T_TOK * K_TOP;
        row = (size_t)offs[E_NUM] + (size_t)t;
    }
    const float* src = x + (size_t)t * H_DIM;
    ushort* dst = Xall + row * H_DIM;
    const int i = threadIdx.x * 8;
    float4 f0 = *(const float4*)(src + i);
    float4 f1 = *(const float4*)(src + i + 4);
    ushort8 v;
    v[0] = f2b(f0.x); v[1] = f2b(f0.y); v[2] = f2b(f0.z); v[3] = f2b(f0.w);
    v[4] = f2b(f1.x); v[5] = f2b(f1.y); v[6] = f2b(f1.z); v[7] = f2b(f1.w);
    *(ushort8*)(dst + i) = v;
}

// ---------------- unified MoE GEMM (m151-faithful 128x128) -----------------
// C[M,N] = A[M,K](bf16) * B[N,K](fp32)^T, 18 experts. 256 threads = 4 waves
// (2x2), per-wave 64x64, acc[4][4]. LDS 48KB -> 3 blocks/CU (m97 occupancy):
//   A: double-buffered global_load_lds 2x16KB (issued during compute, younger
//      than B loads, drained by the vmcnt(0) AFTER a compute+writeB of cover).
//   B: reg-staged fp32 (8 dwordx4, issued FIRST = oldest -> writeB's auto
//      dep-wait is counted vmcnt(4), A stays in flight), cvt_pk -> bf16 sbuf.
// Two raw barriers per K-step around the write phase (m97 pattern); the only
// vmcnt(0) is placed where A has already landed.
// bf16 LDS layout (both): element (r, slot) at shorts [r*64 + ((slot^(r&7))*8)]
// (measured zero bank conflicts, rounds 2/4/6/8).
template<int DOWN>
__global__ __launch_bounds__(256, 3) void moe_gemm_kernel(
    const ushort* __restrict__ Abase,
    const float* __restrict__ Wr1, const float* __restrict__ Wr2,
    const float* __restrict__ Ws1, const float* __restrict__ Ws2,
    ushort* __restrict__ C1, ushort* __restrict__ C2,
    const int* __restrict__ counts, const int* __restrict__ offs,
    int nNT, int lda, int K, int ldc)
{
    __shared__ short Alds[2][128 * 64];     // 2 x 16 KB
    __shared__ short Blds[128 * 64];        // 16 KB  -> 48 KB total

    const int work = xcd_swizzle(blockIdx.x, gridDim.x);
    const int slab = NE_ALL * 8;
    int nt = work / slab;
    const int rem = work - nt * slab;
    const int e = rem >> 3;
    const int mt = rem & 7;

    const int S = offs[E_NUM];
    const int M = (e < E_NUM) ? counts[e] : 1024;
    const int row0 = mt << 7;
    if (row0 >= M) return;
    const int crowbase = (e < E_NUM) ? offs[e] : S + ((e - E_NUM) << 10);
    const int arowbase = DOWN ? crowbase : ((e < E_NUM) ? offs[e] : S);

    const float* B; ushort* C; int ldb, koff = 0;
    if (DOWN) {
        C = C1;
        if (e < E_NUM) { ldb = I_DIM; B = Wr1 + (size_t)e * H_DIM * I_DIM; }
        else           { ldb = 2 * I_DIM; B = Ws1; koff = (e - E_NUM) * I_DIM; }
    } else {
        ldb = H_DIM;
        const float* Bg = (e < E_NUM) ? Wr1 + (size_t)e * I_DIM * H_DIM
                                      : Ws1 + (size_t)(e - E_NUM) * I_DIM * H_DIM;
        const float* Bu = (e < E_NUM) ? Wr2 + (size_t)e * I_DIM * H_DIM
                                      : Ws2 + (size_t)(e - E_NUM) * I_DIM * H_DIM;
        if (nt < nNT) { B = Bg; C = C1; } else { B = Bu; C = C2; nt -= nNT; }
    }
    const int n0 = nt << 7;

    const int tid = threadIdx.x;
    const int lane = tid & 63;
    const int wave = tid >> 6;               // 0..3
    const int wm = wave & 1, wn = wave >> 1; // 2M x 2N
    const int l15 = lane & 15, lhi = lane >> 4;

    const char* __restrict__ Ab = (const char*)(Abase + (size_t)(arowbase + row0) * lda);

    // A staging: 16 chunks of 1KB (8 rows x 128B); wave w stages chunks 4w..4w+3
    int aOff[4];
#pragma unroll
    for (int i = 0; i < 4; ++i) {
        const int chunk = wave * 4 + i;
        const int off = chunk * 1024 + lane * 16;
        const int r = off >> 7, s = (off >> 4) & 7;
        aOff[i] = r * lda * 2 + ((s ^ (r & 7)) << 4);   // bytes; +kt*128 later
    }

    // B staging: thread covers 4 cells (row r, 8-float k-slot s = 32B each):
    // r = (tid>>3) + i*32, s = tid&7. Global coalesced 256B per 8 threads.
    const int br_ = tid >> 3, bs = tid & 7;
    const float* Bc[4]; int bldw[4];
#pragma unroll
    for (int i = 0; i < 4; ++i) {
        const int r = br_ + (i << 5);
        Bc[i] = B + (size_t)(n0 + r) * ldb + koff + (bs << 3);
        bldw[i] = (r << 6) + ((bs ^ (r & 7)) << 3);   // shorts
    }

    f32x4 acc[4][4];
#pragma unroll
    for (int m = 0; m < 4; ++m)
#pragma unroll
        for (int n = 0; n < 4; ++n) acc[m][n] = (f32x4){0.f, 0.f, 0.f, 0.f};

    float4 br[4][2];   // B(kt+1) staging registers (static indexing)

    auto issueB = [&](int kt) {            // 8 loads — ALWAYS ISSUED FIRST
#pragma unroll
        for (int i = 0; i < 4; ++i) {
            const float* src = Bc[i] + (kt << 6);
            br[i][0] = *(const float4*)src;
            br[i][1] = *(const float4*)(src + 4);
        }
    };
    auto issueA = [&](int kt, int pb) {    // 4 gload_lds — issued AFTER B
#pragma unroll
        for (int i = 0; i < 4; ++i)
            gload16(Ab + (size_t)aOff[i] + (size_t)(kt << 7),
                    (char*)Alds[pb] + (wave * 4 + i) * 1024);
    };
    auto writeB = [&]() {                  // auto dep-wait = counted vmcnt(4)
#pragma unroll
        for (int i = 0; i < 4; ++i) {
            union { short8 s; unsigned u[4]; } w;
            w.u[0] = cvt_pk2(br[i][0].x, br[i][0].y);
            w.u[1] = cvt_pk2(br[i][0].z, br[i][0].w);
            w.u[2] = cvt_pk2(br[i][1].x, br[i][1].y);
            w.u[3] = cvt_pk2(br[i][1].z, br[i][1].w);
            *(short8*)&Blds[bldw[i]] = w.s;
        }
    };
    auto compute = [&](int p) {
#pragma unroll
        for (int kk = 0; kk < 2; ++kk) {
            const int kb = (kk << 2) + lhi;
            short8 af[4], bfr[4];
#pragma unroll
            for (int m = 0; m < 4; ++m) {
                const int rA = (wm << 6) + (m << 4) + l15;
                af[m] = *(const short8*)&Alds[p][(rA << 6) + ((kb ^ (rA & 7)) << 3)];
            }
#pragma unroll
            for (int n = 0; n < 4; ++n) {
                const int rB = (wn << 6) + (n << 4) + l15;
                bfr[n] = *(const short8*)&Blds[(rB << 6) + ((kb ^ (rB & 7)) << 3)];
            }
            __builtin_amdgcn_s_setprio(1);
#pragma unroll
            for (int m = 0; m < 4; ++m)
#pragma unroll
                for (int n = 0; n < 4; ++n)
                    acc[m][n] = __builtin_amdgcn_mfma_f32_16x16x32_bf16(
                        af[m], bfr[n], acc[m][n], 0, 0, 0);
            __builtin_amdgcn_s_setprio(0);
        }
    };

    const int nK = K >> 6;   // 32 (gate/up) or 22 (down)
    // ---- prologue: stage tile 0 (one-time exposed drain) ----
    issueB(0); SCHED0();
    issueA(0, 0); SCHED0();
    writeB();                                        // waits br (vmcnt(4))
    asm volatile("s_waitcnt vmcnt(0) lgkmcnt(0)" ::: "memory");
    RBAR(); SCHED0();

    int p = 0;
    for (int kt = 0; kt < nK; ++kt) {
        const bool more = (kt + 1 < nK);
        if (more) {
            issueB(kt + 1); SCHED0();      // oldest: full compute phase of cover
            issueA(kt + 1, p ^ 1); SCHED0();
        }
        compute(p);                        // 16 ds_read_b128 + 32 MFMA per wave
        if (more) {
            RBAR();                        // BARa: all waves done reading LDS(kt)
            writeB();                      // auto vmcnt(4): A(kt+1) stays in flight
            asm volatile("s_waitcnt vmcnt(0) lgkmcnt(0)" ::: "memory");  // A landed
            RBAR(); SCHED0();              // BARb: LDS(kt+1) visible
            p ^= 1;
        }
    }

    // epilogue: C/D layout col=lane&15, row=(lane>>4)*4+j
    const size_t cbase_col = (size_t)n0 + (wn << 6) + l15;
#pragma unroll
    for (int m = 0; m < 4; ++m) {
        const int rloc = (wm << 6) + (m << 4) + (lhi << 2);
#pragma unroll
        for (int j = 0; j < 4; ++j) {
            const int crow = row0 + rloc + j;
            if (crow >= M) continue;
            const size_t co = (size_t)(crowbase + crow) * ldc + cbase_col;
#pragma unroll
            for (int n = 0; n < 4; ++n) C[co + (n << 4)] = f2b(acc[m][n][j]);
        }
    }
}

// ---------------- SwiGLU elementwise: G = silu(G) * U (in place) -----------
__global__ __launch_bounds__(256) void silu_kernel(
    ushort* __restrict__ G, const ushort* __restrict__ U,
    const int* __restrict__ eidx, const int* __restrict__ slotarr,
    const int* __restrict__ offs)
{
    const int b = blockIdx.x;
    size_t row;
    if (b < T_TOK * K_TOP) {
        row = (size_t)offs[eidx[b]] + (size_t)slotarr[b];
    } else {
        row = (size_t)offs[E_NUM] + (size_t)(b - T_TOK * K_TOP);
    }
    ushort* g = G + row * I_DIM;
    const ushort* u = U + row * I_DIM;
    const int i = threadIdx.x * 8;
    if (i < I_DIM) {
        ushort8 gv = *(const ushort8*)(g + i);
        ushort8 uv = *(const ushort8*)(u + i);
        ushort8 hv;
#pragma unroll
        for (int j = 0; j < 8; ++j) {
            float gf = b2f(gv[j]);
            float uf = b2f(uv[j]);
            float sf = gf / (1.f + expf(-gf));
            hv[j] = f2b(sf * uf);
        }
        *(ushort8*)(g + i) = hv;
    }
}

// ---------------- combine: out[t] = sum_k w_k*Y[row] + Y[sh0] + Y[sh1] -----
__global__ __launch_bounds__(256) void combine_kernel(
    float* __restrict__ out, const ushort* __restrict__ Y,
    const float* __restrict__ topw, const int* __restrict__ eidx,
    const int* __restrict__ slotarr, const int* __restrict__ offs)
{
    const int t = blockIdx.x;
    const int i = threadIdx.x * 8;
    const int S = offs[E_NUM];
    float acc[8];
    {
        ushort8 v0 = *(const ushort8*)(Y + ((size_t)S + t) * H_DIM + i);
        ushort8 v1 = *(const ushort8*)(Y + ((size_t)S + 1024 + t) * H_DIM + i);
#pragma unroll
        for (int j = 0; j < 8; ++j) acc[j] = b2f(v0[j]) + b2f(v1[j]);
    }
#pragma unroll
    for (int k = 0; k < K_TOP; ++k) {
        const float w = topw[t * K_TOP + k];
        const size_t row = (size_t)offs[eidx[t * K_TOP + k]] + (size_t)slotarr[t * K_TOP + k];
        ushort8 v = *(const ushort8*)(Y + row * H_DIM + i);
#pragma unroll
        for (int j = 0; j < 8; ++j) acc[j] += w * b2f(v[j]);
    }
    float* o = out + (size_t)t * H_DIM;
    float4 o0, o1;
    o0.x = acc[0]; o0.y = acc[1]; o0.z = acc[2]; o0.w = acc[3];
    o1.x = acc[4]; o1.y = acc[5]; o1.z = acc[6]; o1.w = acc[7];
    *(float4*)(o + i) = o0;
    *(float4*)(o + i + 4) = o1;
}

// ---------------------------------------------------------------------------
extern "C" void kernel_launch(void* const* d_in, const int* in_sizes, int n_in,
                              void* d_out, int out_size, void* d_ws, size_t ws_size,
                              hipStream_t stream) {
    const float* x       = (const float*)d_in[0];
    const float* gate_w  = (const float*)d_in[1];
    const float* w_gate  = (const float*)d_in[2];
    const float* w_up    = (const float*)d_in[3];
    const float* w_down  = (const float*)d_in[4];
    const float* sw_gate = (const float*)d_in[5];
    const float* sw_up   = (const float*)d_in[6];
    const float* sw_down = (const float*)d_in[7];
    float* out = (float*)d_out;

    char* p = (char*)d_ws;
    auto take = [&](size_t b) { char* r = p; p += (b + 255) & ~(size_t)255; return r; };
    int*    counts = (int*)take(32 * 4);
    int*    offs   = (int*)take(32 * 4);
    float*  topw   = (float*)take((size_t)T_TOK * K_TOP * 4);
    int*    eidx   = (int*)take((size_t)T_TOK * K_TOP * 4);
    int*    slot   = (int*)take((size_t)T_TOK * K_TOP * 4);
    ushort* Xall   = (ushort*)take((size_t)(PADCAP + 1024) * H_DIM * 2);
    ushort* G      = (ushort*)take((size_t)(PADCAP + 2048) * I_DIM * 2);
    ushort* U      = (ushort*)take((size_t)(PADCAP + 2048) * I_DIM * 2);
    ushort* Y      = (ushort*)take((size_t)(PADCAP + 2048) * H_DIM * 2);

    zero_counts_kernel<<<1, 64, 0, stream>>>(counts);
    router_kernel<<<T_TOK, 256, 0, stream>>>(x, gate_w, topw, eidx, slot, counts);
    prefix_kernel<<<1, 64, 0, stream>>>(counts, offs);
    gather_cvt_kernel<<<T_TOK * K_TOP + T_TOK, 256, 0, stream>>>(x, eidx, slot, offs, Xall);

    // gate/up: 22 n-tiles (11 gate + 11 up, BN=128) x 18 experts x 8 m-tiles
    moe_gemm_kernel<0><<<22 * NE_ALL * 8, 256, 0, stream>>>(
        Xall, w_gate, w_up, sw_gate, sw_up, G, U, counts, offs,
        11, H_DIM /*lda*/, H_DIM /*K*/, I_DIM /*ldc*/);
    silu_kernel<<<T_TOK * K_TOP + 2048, 256, 0, stream>>>(G, U, eidx, slot, offs);
    // down: 16 n-tiles x 18 experts x 8 m-tiles, K=1408, A stride I_DIM
    moe_gemm_kernel<1><<<16 * NE_ALL * 8, 256, 0, stream>>>(
        G, w_down, nullptr, sw_down, nullptr, Y, nullptr, counts, offs,
        16, I_DIM /*lda*/, I_DIM /*K*/, H_DIM /*ldc*/);

    combine_kernel<<<T_TOK, 256, 0, stream>>>(out, Y, topw, eidx, slot, offs);
}